// Round 5
// baseline (288.337 us; speedup 1.0000x reference)
//
#include <hip/hip_runtime.h>
#include <math.h>

#define GRID_D 362
#define NKEYS  10000
#define EPSV   1e-8f
#define MROWS  8
#define NTHR   256
#define RPB    16    // rows per prep block

__device__ __forceinline__ float rfl(float x) {
    return __int_as_float(__builtin_amdgcn_readfirstlane(__float_as_int(x)));
}

// ---------- prep (16 rows/block, LDS histogram -> 3 atomics/block) + pack ----------
__global__ __launch_bounds__(256) void prep_pack_kernel(
    const float* __restrict__ batch_x,
    const int*   __restrict__ batch_a,
    const float* __restrict__ keys,      // [3*10000, 6]
    const float* __restrict__ values,    // [3*10000, 7]
    int*   __restrict__ cnt,             // [4] zeroed
    int*   __restrict__ rowlist,         // [3*B]
    float* __restrict__ qout,            // [B*6]
    int*   __restrict__ cellout,         // [B*6]
    float* __restrict__ packed,          // [3*10000, 16]
    int B, int prep_blocks)
{
    if ((int)blockIdx.x >= prep_blocks) {
        // ---- pack: one thread per key-row ----
        const int i = (blockIdx.x - prep_blocks) * 256 + threadIdx.x;
        if (i >= 3 * NKEYS) return;
        const float* k = keys   + (size_t)i * 6;
        const float* v = values + (size_t)i * 7;
        const float k0 = k[0], k1 = k[1], k2 = k[2], k3 = k[3], k4 = k[4], k5 = k[5];
        const float nn = k0*k0 + k1*k1 + k2*k2 + k3*k3 + k4*k4 + k5*k5;
        const float invn = 1.f / (sqrtf(nn) + EPSV);
        float4* p = (float4*)(packed + (size_t)i * 16);
        p[0] = make_float4(k0*invn, k1*invn, k2*invn, k3*invn);
        p[1] = make_float4(k4*invn, k5*invn, v[0], v[1]);
        p[2] = make_float4(v[2], v[3], v[4], v[5]);
        p[3] = make_float4(v[6], 0.f, 0.f, 0.f);
        return;
    }

    __shared__ int sh_a[RPB];
    __shared__ int sh_hist[3];
    __shared__ int sh_base[3];
    const int tid  = threadIdx.x;
    const int lane = tid & 63;
    const int w    = tid >> 6;
    if (tid < 3) sh_hist[tid] = 0;
    __syncthreads();

    const int b0 = blockIdx.x * RPB;
    for (int rr = 0; rr < RPB / 4; ++rr) {
        const int i = rr * 4 + w;
        const int b = b0 + i;
        if (b >= B) continue;                       // wave-uniform
        const float* x = batch_x + (size_t)b * GRID_D;
        float bestv = -INFINITY;
        int   besti = 1 << 30;
        for (int c = lane; c < GRID_D; c += 64) {
            const float vv = x[c];
            if (vv > bestv || (vv == bestv && c < besti)) { bestv = vv; besti = c; }
        }
#pragma unroll
        for (int off = 32; off > 0; off >>= 1) {
            const float ov = __shfl_down(bestv, off);
            const int   oi = __shfl_down(besti, off);
            if (ov > bestv || (ov == bestv && oi < besti)) { bestv = ov; besti = oi; }
        }
        if (lane == 0) {
            const int ptr = besti;
            int cells[6];
            cells[0] = 0;
            cells[1] = ptr;
            cells[2] = min(max(ptr - 19, 1), GRID_D - 1);
            cells[3] = min(max(ptr + 19, 1), GRID_D - 1);
            cells[4] = min(max(ptr - 1,  1), GRID_D - 1);
            cells[5] = min(max(ptr + 1,  1), GRID_D - 1);
            float att[6], ss = 0.f;
#pragma unroll
            for (int j = 0; j < 6; ++j) { att[j] = x[cells[j]]; ss += att[j] * att[j]; }
            const float inv = 1.f / (sqrtf(ss) + EPSV);
#pragma unroll
            for (int j = 0; j < 6; ++j) {
                qout[b * 6 + j]    = att[j] * inv;
                cellout[b * 6 + j] = cells[j];
            }
            const int a = batch_a[b];
            sh_a[i] = a;
            atomicAdd(&sh_hist[a], 1);              // LDS atomic
        }
    }
    __syncthreads();
    if (tid == 0) {
#pragma unroll
        for (int a = 0; a < 3; ++a) sh_base[a] = atomicAdd(&cnt[a], sh_hist[a]);
    }
    __syncthreads();
    if (tid < RPB && b0 + tid < B) {
        const int a = sh_a[tid];
        int pos = 0;
        for (int j = 0; j < tid; ++j) pos += (sh_a[j] == a) ? 1 : 0;
        rowlist[a * B + sh_base[a] + pos] = b0 + tid;
    }
}

// ---------- main: 8 rows/block, z = key-split, last-block-per-chunk finalizes ----------
template <int PACKED>
__global__ __launch_bounds__(NTHR) void main_kernel(
    const float* __restrict__ batch_x,
    const float* __restrict__ keys,
    const float* __restrict__ values,
    const float* __restrict__ packed,
    const int*   __restrict__ cnt,
    const int*   __restrict__ rowlist,
    const float* __restrict__ qin,
    const int*   __restrict__ cellin,
    float* __restrict__ partial,         // [nz][B][9]
    int*   __restrict__ ctr,             // [3 * chunks] zeroed
    float* __restrict__ out_x,
    float* __restrict__ out_unc,
    float* __restrict__ out_done,
    int B, int kps)
{
    const int a     = blockIdx.y;
    const int chunk = blockIdx.x;
    const int base  = chunk * MROWS;
    const int count = cnt[a];
    if (base >= count) return;
    const int tid    = threadIdx.x;
    const int lane   = tid & 63;
    const int w      = tid >> 6;
    const int z      = blockIdx.z;
    const int chunks = gridDim.x;
    const int nz     = gridDim.z;

    __shared__ int   s_row[MROWS];
    __shared__ float s_q[MROWS][6];
    __shared__ int   s_cell[MROWS][6];
    __shared__ float s_red[4][64];
    __shared__ float s_redm[4][MROWS];
    __shared__ float s_tot[MROWS][9];
    __shared__ float s_delta[MROWS][6];
    __shared__ int   s_last;

    if (tid < MROWS)
        s_row[tid] = (base + tid < count) ? rowlist[a * B + base + tid] : -1;
    if (tid < MROWS * 6) {
        const int r = tid / 6, j = tid % 6;
        const int row = (base + r < count) ? rowlist[a * B + base + r] : -1;
        s_q[r][j]    = (row >= 0) ? qin[row * 6 + j]    : 0.f;
        s_cell[r][j] = (row >= 0) ? cellin[row * 6 + j] : 0;
    }
    __syncthreads();

    // wave-uniform query coefficients (SGPRs)
    float qs[MROWS][6];
#pragma unroll
    for (int r = 0; r < MROWS; ++r)
#pragma unroll
        for (int j = 0; j < 6; ++j) qs[r][j] = rfl(s_q[r][j]);

    float acc[64];
    float m[MROWS];
#pragma unroll
    for (int i = 0; i < 64; ++i) acc[i] = 0.f;
#pragma unroll
    for (int r = 0; r < MROWS; ++r) m[r] = -INFINITY;

    const int n0 = z * kps;
    const int n1 = min(n0 + kps, NKEYS);

    if (PACKED) {
        const float4* __restrict__ pk = (const float4*)packed + (size_t)a * NKEYS * 4;
        for (int n = n0 + tid; n < n1; n += 2 * NTHR) {
            const int  n2 = n + NTHR;
            const bool h2 = (n2 < n1);
            const float4 A0 = pk[n * 4 + 0], A1 = pk[n * 4 + 1],
                         A2 = pk[n * 4 + 2], A3 = pk[n * 4 + 3];
            float4 B0, B1, B2, B3;
            if (h2) { B0 = pk[n2 * 4 + 0]; B1 = pk[n2 * 4 + 1];
                      B2 = pk[n2 * 4 + 2]; B3 = pk[n2 * 4 + 3]; }
            {
                const float v0 = A1.z, v1 = A1.w, v2 = A2.x, v3 = A2.y,
                            v4 = A2.z, v5 = A2.w, v6 = A3.x;
#pragma unroll
                for (int r = 0; r < MROWS; ++r) {
                    const float s = qs[r][0]*A0.x + qs[r][1]*A0.y + qs[r][2]*A0.z +
                                    qs[r][3]*A0.w + qs[r][4]*A1.x + qs[r][5]*A1.y;
                    m[r] = fmaxf(m[r], s);
                    const float e = __expf(s - 1.f);   // sim<=1; softmax shift-invariant
                    acc[r*8+0] += e;
                    acc[r*8+1] += e*v0; acc[r*8+2] += e*v1; acc[r*8+3] += e*v2;
                    acc[r*8+4] += e*v3; acc[r*8+5] += e*v4; acc[r*8+6] += e*v5;
                    acc[r*8+7] += e*v6;
                }
            }
            if (h2) {
                const float v0 = B1.z, v1 = B1.w, v2 = B2.x, v3 = B2.y,
                            v4 = B2.z, v5 = B2.w, v6 = B3.x;
#pragma unroll
                for (int r = 0; r < MROWS; ++r) {
                    const float s = qs[r][0]*B0.x + qs[r][1]*B0.y + qs[r][2]*B0.z +
                                    qs[r][3]*B0.w + qs[r][4]*B1.x + qs[r][5]*B1.y;
                    m[r] = fmaxf(m[r], s);
                    const float e = __expf(s - 1.f);
                    acc[r*8+0] += e;
                    acc[r*8+1] += e*v0; acc[r*8+2] += e*v1; acc[r*8+3] += e*v2;
                    acc[r*8+4] += e*v3; acc[r*8+5] += e*v4; acc[r*8+6] += e*v5;
                    acc[r*8+7] += e*v6;
                }
            }
        }
    } else {
        const float* __restrict__ krow = keys   + (size_t)a * NKEYS * 6;
        const float* __restrict__ vrow = values + (size_t)a * NKEYS * 7;
        for (int n = n0 + tid; n < n1; n += NTHR) {
            const float* kp = krow + n * 6;
            const float2 k01 = *(const float2*)(kp);
            const float2 k23 = *(const float2*)(kp + 2);
            const float2 k45 = *(const float2*)(kp + 4);
            const float nn = k01.x*k01.x + k01.y*k01.y + k23.x*k23.x +
                             k23.y*k23.y + k45.x*k45.x + k45.y*k45.y;
            const float invn = 1.f / (sqrtf(nn) + EPSV);
            const float* vp = vrow + n * 7;
            const float v0 = vp[0], v1 = vp[1], v2 = vp[2], v3 = vp[3],
                        v4 = vp[4], v5 = vp[5], v6 = vp[6];
#pragma unroll
            for (int r = 0; r < MROWS; ++r) {
                const float dot = qs[r][0]*k01.x + qs[r][1]*k01.y + qs[r][2]*k23.x +
                                  qs[r][3]*k23.y + qs[r][4]*k45.x + qs[r][5]*k45.y;
                const float s = dot * invn;
                m[r] = fmaxf(m[r], s);
                const float e = __expf(s - 1.f);
                acc[r*8+0] += e;
                acc[r*8+1] += e*v0; acc[r*8+2] += e*v1; acc[r*8+3] += e*v2;
                acc[r*8+4] += e*v3; acc[r*8+5] += e*v4; acc[r*8+6] += e*v5;
                acc[r*8+7] += e*v6;
            }
        }
    }

    // ---- in-wave log reduce-scatter: lane l ends owning flat value l ----
#pragma unroll
    for (int bit = 32; bit >= 1; bit >>= 1) {
        const bool up = (lane & bit) != 0;
#pragma unroll
        for (int i = 0; i < bit; ++i) {
            const float send = up ? acc[i] : acc[i + bit];
            const float recv = __shfl_xor(send, bit);
            acc[i] = (up ? acc[i + bit] : acc[i]) + recv;
        }
    }
#pragma unroll
    for (int bit = 32; bit >= 8; bit >>= 1) {
        const int  c  = bit >> 3;
        const bool up = (lane & bit) != 0;
#pragma unroll
        for (int i = 0; i < c; ++i) {
            const float send = up ? m[i] : m[i + c];
            const float recv = __shfl_xor(send, bit);
            m[i] = fmaxf(up ? m[i + c] : m[i], recv);
        }
    }
    float m0 = m[0];
#pragma unroll
    for (int bit = 4; bit >= 1; bit >>= 1) m0 = fmaxf(m0, __shfl_xor(m0, bit));

    s_red[w][lane] = acc[0];
    if ((lane & 7) == 0) s_redm[w][lane >> 3] = m0;
    __syncthreads();

    // ---- cross-wave combine, write partials ----
    if (tid < 64) {
        const float t = s_red[0][tid] + s_red[1][tid] + s_red[2][tid] + s_red[3][tid];
        const int r = tid >> 3, row = s_row[r];
        if (row >= 0) partial[((size_t)z * B + row) * 9 + (tid & 7)] = t;
    } else if (tid < 64 + MROWS) {
        const int r = tid - 64;
        const float mm = fmaxf(fmaxf(s_redm[0][r], s_redm[1][r]),
                               fmaxf(s_redm[2][r], s_redm[3][r]));
        const int row = s_row[r];
        if (row >= 0) partial[((size_t)z * B + row) * 9 + 8] = mm;
    }

    // ---- split-K completion: last z-block for this (a,chunk) finalizes ----
    __threadfence();
    if (tid == 0) {
        const int old = atomicAdd(&ctr[a * chunks + chunk], 1);
        s_last = (old == nz - 1) ? 1 : 0;
    }
    __syncthreads();
    if (!s_last) return;
    __threadfence();

    if (tid < MROWS * 9) {
        const int r = tid / 9, p = tid % 9;
        const int row = s_row[r];
        if (row >= 0) {
            float v = partial[((size_t)0 * B + row) * 9 + p];
            for (int zz = 1; zz < nz; ++zz) {
                const float u = partial[((size_t)zz * B + row) * 9 + p];
                v = (p == 8) ? fmaxf(v, u) : (v + u);
            }
            s_tot[r][p] = v;
        }
    }
    __syncthreads();
    if (tid < MROWS) {
        const int r = tid, row = s_row[r];
        if (row >= 0) {
            const float inv = 1.f / s_tot[r][0];
#pragma unroll
            for (int j = 0; j < 6; ++j) s_delta[r][j] = s_tot[r][1 + j] * inv;
            out_done[row] = s_tot[r][7] * inv;
            out_unc[row]  = -s_tot[r][8];
        }
    }
    __syncthreads();

    // ---- scatter deltas (ascending j -> last write wins) + copy rows ----
    for (int f = tid; f < MROWS * GRID_D; f += NTHR) {
        const int r = f / GRID_D;
        const int c = f - r * GRID_D;
        const int row = s_row[r];
        if (row < 0) continue;
        float add = 0.f;
#pragma unroll
        for (int j = 0; j < 6; ++j)
            if (s_cell[r][j] == c) add = s_delta[r][j];
        out_x[(size_t)row * GRID_D + c] = batch_x[(size_t)row * GRID_D + c] + add;
    }
}

extern "C" void kernel_launch(void* const* d_in, const int* in_sizes, int n_in,
                              void* d_out, int out_size, void* d_ws, size_t ws_size,
                              hipStream_t stream) {
    const float* batch_x = (const float*)d_in[0];
    const int*   batch_a = (const int*)d_in[1];
    const float* keys    = (const float*)d_in[2];
    const float* values  = (const float*)d_in[3];
    const int B = in_sizes[1];                 // 4096

    float* out      = (float*)d_out;
    float* out_x    = out;
    float* out_unc  = out + (size_t)B * GRID_D;
    float* out_done = out_unc + B;

    const int chunks = (B + MROWS - 1) / MROWS;      // 512

    // workspace layout (zeroed region first)
    int*   cnt     = (int*)d_ws;                         // 4 ints
    int*   ctr     = cnt + 4;                            // 3*chunks ints
    int*   rowlist = ctr + 3 * chunks;                   // 3*B ints
    float* qbuf    = (float*)(rowlist + 3 * B);          // B*6 floats
    int*   cellbuf = (int*)(qbuf + (size_t)B * 6);       // B*6 ints
    float* partial = (float*)(cellbuf + (size_t)B * 6);  // ksplit*B*9 floats
    // packed goes after the largest ksplit's partial
    const size_t fixed_elems = (size_t)4 + 3 * chunks + 3 * B + 6 * B + 6 * B;
    const size_t pack_elems  = (size_t)3 * NKEYS * 16;

    int ksplit = 4;
    if (ws_size < (fixed_elems + (size_t)ksplit * B * 9 + pack_elems) * 4) ksplit = 1;
    float* packed = (float*)(partial + (size_t)ksplit * B * 9);
    const int do_pack =
        (ws_size >= (fixed_elems + (size_t)ksplit * B * 9 + pack_elems) * 4) ? 1 : 0;

    hipMemsetAsync(cnt, 0, (4 + 3 * chunks) * sizeof(int), stream);

    const int prep_blocks = (B + RPB - 1) / RPB;
    const int pack_blocks = do_pack ? (3 * NKEYS + 255) / 256 : 0;
    prep_pack_kernel<<<dim3(prep_blocks + pack_blocks), 256, 0, stream>>>(
        batch_x, batch_a, keys, values, cnt, rowlist, qbuf, cellbuf,
        packed, B, prep_blocks);

    const int kps = (NKEYS + ksplit - 1) / ksplit;
    const dim3 grid(chunks, 3, ksplit);
    if (do_pack)
        main_kernel<1><<<grid, NTHR, 0, stream>>>(
            batch_x, keys, values, packed, cnt, rowlist, qbuf, cellbuf,
            partial, ctr, out_x, out_unc, out_done, B, kps);
    else
        main_kernel<0><<<grid, NTHR, 0, stream>>>(
            batch_x, keys, values, packed, cnt, rowlist, qbuf, cellbuf,
            partial, ctr, out_x, out_unc, out_done, B, kps);
}

// Round 6
// 78.817 us; speedup vs baseline: 3.6583x; 3.6583x over previous
//
#include <hip/hip_runtime.h>
#include <math.h>

#define GRID_D 362
#define NKEYS  10000
#define EPSV   1e-8f
#define MROWS  8
#define NTHR   256
#define RPB    16    // rows per prep block
#define KSPLIT 4

__device__ __forceinline__ float rfl(float x) {
    return __int_as_float(__builtin_amdgcn_readfirstlane(__float_as_int(x)));
}

// ---------- prep (16 rows/block, LDS histogram -> 3 atomics/block) + pack ----------
__global__ __launch_bounds__(256) void prep_pack_kernel(
    const float* __restrict__ batch_x,
    const int*   __restrict__ batch_a,
    const float* __restrict__ keys,      // [3*10000, 6]
    const float* __restrict__ values,    // [3*10000, 7]
    int*   __restrict__ cnt,             // [4] zeroed
    int*   __restrict__ rowlist,         // [3*B]
    float* __restrict__ qout,            // [B*6]
    int*   __restrict__ cellout,         // [B*6]
    float* __restrict__ packed,          // [3*10000, 16]
    int B, int prep_blocks)
{
    if ((int)blockIdx.x >= prep_blocks) {
        // ---- pack: one thread per key-row ----
        const int i = (blockIdx.x - prep_blocks) * 256 + threadIdx.x;
        if (i >= 3 * NKEYS) return;
        const float* k = keys   + (size_t)i * 6;
        const float* v = values + (size_t)i * 7;
        const float k0 = k[0], k1 = k[1], k2 = k[2], k3 = k[3], k4 = k[4], k5 = k[5];
        const float nn = k0*k0 + k1*k1 + k2*k2 + k3*k3 + k4*k4 + k5*k5;
        const float invn = 1.f / (sqrtf(nn) + EPSV);
        float4* p = (float4*)(packed + (size_t)i * 16);
        p[0] = make_float4(k0*invn, k1*invn, k2*invn, k3*invn);
        p[1] = make_float4(k4*invn, k5*invn, v[0], v[1]);
        p[2] = make_float4(v[2], v[3], v[4], v[5]);
        p[3] = make_float4(v[6], 0.f, 0.f, 0.f);
        return;
    }

    __shared__ int sh_a[RPB];
    __shared__ int sh_hist[3];
    __shared__ int sh_base[3];
    const int tid  = threadIdx.x;
    const int lane = tid & 63;
    const int w    = tid >> 6;
    if (tid < 3) sh_hist[tid] = 0;
    __syncthreads();

    const int b0 = blockIdx.x * RPB;
    for (int rr = 0; rr < RPB / 4; ++rr) {
        const int i = rr * 4 + w;
        const int b = b0 + i;
        if (b >= B) continue;                       // wave-uniform
        const float* x = batch_x + (size_t)b * GRID_D;
        float bestv = -INFINITY;
        int   besti = 1 << 30;
        for (int c = lane; c < GRID_D; c += 64) {
            const float vv = x[c];
            if (vv > bestv || (vv == bestv && c < besti)) { bestv = vv; besti = c; }
        }
#pragma unroll
        for (int off = 32; off > 0; off >>= 1) {
            const float ov = __shfl_down(bestv, off);
            const int   oi = __shfl_down(besti, off);
            if (ov > bestv || (ov == bestv && oi < besti)) { bestv = ov; besti = oi; }
        }
        if (lane == 0) {
            const int ptr = besti;
            int cells[6];
            cells[0] = 0;
            cells[1] = ptr;
            cells[2] = min(max(ptr - 19, 1), GRID_D - 1);
            cells[3] = min(max(ptr + 19, 1), GRID_D - 1);
            cells[4] = min(max(ptr - 1,  1), GRID_D - 1);
            cells[5] = min(max(ptr + 1,  1), GRID_D - 1);
            float att[6], ss = 0.f;
#pragma unroll
            for (int j = 0; j < 6; ++j) { att[j] = x[cells[j]]; ss += att[j] * att[j]; }
            const float inv = 1.f / (sqrtf(ss) + EPSV);
#pragma unroll
            for (int j = 0; j < 6; ++j) {
                qout[b * 6 + j]    = att[j] * inv;
                cellout[b * 6 + j] = cells[j];
            }
            const int a = batch_a[b];
            sh_a[i] = a;
            atomicAdd(&sh_hist[a], 1);              // LDS atomic
        }
    }
    __syncthreads();
    if (tid == 0) {
#pragma unroll
        for (int a = 0; a < 3; ++a) sh_base[a] = atomicAdd(&cnt[a], sh_hist[a]);
    }
    __syncthreads();
    if (tid < RPB && b0 + tid < B) {
        const int a = sh_a[tid];
        int pos = 0;
        for (int j = 0; j < tid; ++j) pos += (sh_a[j] == a) ? 1 : 0;
        rowlist[a * B + sh_base[a] + pos] = b0 + tid;
    }
}

// ---------- main: 8 rows/block, z = key-slice, write partials only ----------
template <int PACKED>
__global__ __launch_bounds__(NTHR) void main_kernel(
    const float* __restrict__ keys,
    const float* __restrict__ values,
    const float* __restrict__ packed,
    const int*   __restrict__ cnt,
    const int*   __restrict__ rowlist,
    const float* __restrict__ qin,
    float* __restrict__ partial,         // [KSPLIT][B][9]
    int B, int kps)
{
    const int a     = blockIdx.y;
    const int base  = blockIdx.x * MROWS;
    const int count = cnt[a];
    if (base >= count) return;
    const int tid  = threadIdx.x;
    const int lane = tid & 63;
    const int w    = tid >> 6;
    const int z    = blockIdx.z;

    __shared__ int   s_row[MROWS];
    __shared__ float s_q[MROWS][6];
    __shared__ float s_red[4][64];
    __shared__ float s_redm[4][MROWS];

    if (tid < MROWS)
        s_row[tid] = (base + tid < count) ? rowlist[a * B + base + tid] : -1;
    if (tid < MROWS * 6) {
        const int r = tid / 6, j = tid % 6;
        const int row = (base + r < count) ? rowlist[a * B + base + r] : -1;
        s_q[r][j] = (row >= 0) ? qin[row * 6 + j] : 0.f;
    }
    __syncthreads();

    // wave-uniform query coefficients (SGPRs)
    float qs[MROWS][6];
#pragma unroll
    for (int r = 0; r < MROWS; ++r)
#pragma unroll
        for (int j = 0; j < 6; ++j) qs[r][j] = rfl(s_q[r][j]);

    float acc[64];
    float m[MROWS];
#pragma unroll
    for (int i = 0; i < 64; ++i) acc[i] = 0.f;
#pragma unroll
    for (int r = 0; r < MROWS; ++r) m[r] = -INFINITY;

    const int n0 = z * kps;
    const int n1 = min(n0 + kps, NKEYS);

    if (PACKED) {
        const float4* __restrict__ pk = (const float4*)packed + (size_t)a * NKEYS * 4;
        for (int n = n0 + tid; n < n1; n += 2 * NTHR) {
            const int  n2 = n + NTHR;
            const bool h2 = (n2 < n1);
            const float4 A0 = pk[n * 4 + 0], A1 = pk[n * 4 + 1],
                         A2 = pk[n * 4 + 2], A3 = pk[n * 4 + 3];
            float4 B0, B1, B2, B3;
            if (h2) { B0 = pk[n2 * 4 + 0]; B1 = pk[n2 * 4 + 1];
                      B2 = pk[n2 * 4 + 2]; B3 = pk[n2 * 4 + 3]; }
            {
                const float v0 = A1.z, v1 = A1.w, v2 = A2.x, v3 = A2.y,
                            v4 = A2.z, v5 = A2.w, v6 = A3.x;
#pragma unroll
                for (int r = 0; r < MROWS; ++r) {
                    const float s = qs[r][0]*A0.x + qs[r][1]*A0.y + qs[r][2]*A0.z +
                                    qs[r][3]*A0.w + qs[r][4]*A1.x + qs[r][5]*A1.y;
                    m[r] = fmaxf(m[r], s);
                    const float e = __expf(s - 1.f);   // sim<=1; softmax shift-invariant
                    acc[r*8+0] += e;
                    acc[r*8+1] += e*v0; acc[r*8+2] += e*v1; acc[r*8+3] += e*v2;
                    acc[r*8+4] += e*v3; acc[r*8+5] += e*v4; acc[r*8+6] += e*v5;
                    acc[r*8+7] += e*v6;
                }
            }
            if (h2) {
                const float v0 = B1.z, v1 = B1.w, v2 = B2.x, v3 = B2.y,
                            v4 = B2.z, v5 = B2.w, v6 = B3.x;
#pragma unroll
                for (int r = 0; r < MROWS; ++r) {
                    const float s = qs[r][0]*B0.x + qs[r][1]*B0.y + qs[r][2]*B0.z +
                                    qs[r][3]*B0.w + qs[r][4]*B1.x + qs[r][5]*B1.y;
                    m[r] = fmaxf(m[r], s);
                    const float e = __expf(s - 1.f);
                    acc[r*8+0] += e;
                    acc[r*8+1] += e*v0; acc[r*8+2] += e*v1; acc[r*8+3] += e*v2;
                    acc[r*8+4] += e*v3; acc[r*8+5] += e*v4; acc[r*8+6] += e*v5;
                    acc[r*8+7] += e*v6;
                }
            }
        }
    } else {
        const float* __restrict__ krow = keys   + (size_t)a * NKEYS * 6;
        const float* __restrict__ vrow = values + (size_t)a * NKEYS * 7;
        for (int n = n0 + tid; n < n1; n += NTHR) {
            const float* kp = krow + n * 6;
            const float2 k01 = *(const float2*)(kp);
            const float2 k23 = *(const float2*)(kp + 2);
            const float2 k45 = *(const float2*)(kp + 4);
            const float nn = k01.x*k01.x + k01.y*k01.y + k23.x*k23.x +
                             k23.y*k23.y + k45.x*k45.x + k45.y*k45.y;
            const float invn = 1.f / (sqrtf(nn) + EPSV);
            const float* vp = vrow + n * 7;
            const float v0 = vp[0], v1 = vp[1], v2 = vp[2], v3 = vp[3],
                        v4 = vp[4], v5 = vp[5], v6 = vp[6];
#pragma unroll
            for (int r = 0; r < MROWS; ++r) {
                const float dot = qs[r][0]*k01.x + qs[r][1]*k01.y + qs[r][2]*k23.x +
                                  qs[r][3]*k23.y + qs[r][4]*k45.x + qs[r][5]*k45.y;
                const float s = dot * invn;
                m[r] = fmaxf(m[r], s);
                const float e = __expf(s - 1.f);
                acc[r*8+0] += e;
                acc[r*8+1] += e*v0; acc[r*8+2] += e*v1; acc[r*8+3] += e*v2;
                acc[r*8+4] += e*v3; acc[r*8+5] += e*v4; acc[r*8+6] += e*v5;
                acc[r*8+7] += e*v6;
            }
        }
    }

    // ---- in-wave log reduce-scatter: lane l ends owning flat value l ----
#pragma unroll
    for (int bit = 32; bit >= 1; bit >>= 1) {
        const bool up = (lane & bit) != 0;
#pragma unroll
        for (int i = 0; i < bit; ++i) {
            const float send = up ? acc[i] : acc[i + bit];
            const float recv = __shfl_xor(send, bit);
            acc[i] = (up ? acc[i + bit] : acc[i]) + recv;
        }
    }
#pragma unroll
    for (int bit = 32; bit >= 8; bit >>= 1) {
        const int  c  = bit >> 3;
        const bool up = (lane & bit) != 0;
#pragma unroll
        for (int i = 0; i < c; ++i) {
            const float send = up ? m[i] : m[i + c];
            const float recv = __shfl_xor(send, bit);
            m[i] = fmaxf(up ? m[i + c] : m[i], recv);
        }
    }
    float m0 = m[0];
#pragma unroll
    for (int bit = 4; bit >= 1; bit >>= 1) m0 = fmaxf(m0, __shfl_xor(m0, bit));

    s_red[w][lane] = acc[0];
    if ((lane & 7) == 0) s_redm[w][lane >> 3] = m0;
    __syncthreads();

    // ---- cross-wave combine, write partials (no fences: finalize is a new kernel) ----
    if (tid < 64) {
        const float t = s_red[0][tid] + s_red[1][tid] + s_red[2][tid] + s_red[3][tid];
        const int r = tid >> 3, row = s_row[r];
        if (row >= 0) partial[((size_t)z * B + row) * 9 + (tid & 7)] = t;
    } else if (tid < 64 + MROWS) {
        const int r = tid - 64;
        const float mm = fmaxf(fmaxf(s_redm[0][r], s_redm[1][r]),
                               fmaxf(s_redm[2][r], s_redm[3][r]));
        const int row = s_row[r];
        if (row >= 0) partial[((size_t)z * B + row) * 9 + 8] = mm;
    }
}

// ---------- finalize: combine splits per row, write outputs (8 rows/block) ----------
__global__ __launch_bounds__(256) void final_kernel(
    const float* __restrict__ batch_x,
    const float* __restrict__ partial,   // [KSPLIT][B][9]
    const int*   __restrict__ cellin,
    float* __restrict__ out_x,
    float* __restrict__ out_unc,
    float* __restrict__ out_done,
    int B)
{
    const int b0  = blockIdx.x * MROWS;
    const int tid = threadIdx.x;

    __shared__ float s_tot[MROWS][9];
    __shared__ float s_delta[MROWS][6];
    __shared__ int   s_cell[MROWS][6];

    if (tid < MROWS * 9) {
        const int r = tid / 9, p = tid % 9;
        const int row = b0 + r;
        if (row < B) {
            float v = partial[(size_t)row * 9 + p];
#pragma unroll
            for (int z = 1; z < KSPLIT; ++z) {
                const float u = partial[((size_t)z * B + row) * 9 + p];
                v = (p == 8) ? fmaxf(v, u) : (v + u);
            }
            s_tot[r][p] = v;
        }
    }
    if (tid >= 128 && tid < 128 + MROWS * 6) {
        const int t = tid - 128, r = t / 6, j = t % 6;
        if (b0 + r < B) s_cell[r][j] = cellin[(b0 + r) * 6 + j];
    }
    __syncthreads();
    if (tid < MROWS) {
        const int r = tid, row = b0 + r;
        if (row < B) {
            const float inv = 1.f / s_tot[r][0];
#pragma unroll
            for (int j = 0; j < 6; ++j) s_delta[r][j] = s_tot[r][1 + j] * inv;
            out_done[row] = s_tot[r][7] * inv;
            out_unc[row]  = -s_tot[r][8];
        }
    }
    __syncthreads();

    for (int f = tid; f < MROWS * GRID_D; f += 256) {
        const int r = f / GRID_D;
        const int c = f - r * GRID_D;
        const int row = b0 + r;
        if (row >= B) continue;
        float add = 0.f;
#pragma unroll
        for (int j = 0; j < 6; ++j)
            if (s_cell[r][j] == c) add = s_delta[r][j];   // ascending j: last wins
        out_x[(size_t)row * GRID_D + c] = batch_x[(size_t)row * GRID_D + c] + add;
    }
}

extern "C" void kernel_launch(void* const* d_in, const int* in_sizes, int n_in,
                              void* d_out, int out_size, void* d_ws, size_t ws_size,
                              hipStream_t stream) {
    const float* batch_x = (const float*)d_in[0];
    const int*   batch_a = (const int*)d_in[1];
    const float* keys    = (const float*)d_in[2];
    const float* values  = (const float*)d_in[3];
    const int B = in_sizes[1];                 // 4096

    float* out      = (float*)d_out;
    float* out_x    = out;
    float* out_unc  = out + (size_t)B * GRID_D;
    float* out_done = out_unc + B;

    const int chunks = (B + MROWS - 1) / MROWS;      // 512

    // workspace layout
    int*   cnt     = (int*)d_ws;                         // 4 ints (zeroed)
    int*   rowlist = cnt + 4;                            // 3*B ints
    float* qbuf    = (float*)(rowlist + 3 * B);          // B*6 floats
    int*   cellbuf = (int*)(qbuf + (size_t)B * 6);       // B*6 ints
    float* partial = (float*)(cellbuf + (size_t)B * 6);  // KSPLIT*B*9 floats
    float* packed  = (float*)(partial + (size_t)KSPLIT * B * 9);

    const size_t fixed_elems = (size_t)4 + 3 * B + 6 * B + 6 * B + (size_t)KSPLIT * B * 9;
    const size_t pack_elems  = (size_t)3 * NKEYS * 16;
    const int do_pack = (ws_size >= (fixed_elems + pack_elems) * 4) ? 1 : 0;

    hipMemsetAsync(cnt, 0, 4 * sizeof(int), stream);

    const int prep_blocks = (B + RPB - 1) / RPB;
    const int pack_blocks = do_pack ? (3 * NKEYS + 255) / 256 : 0;
    prep_pack_kernel<<<dim3(prep_blocks + pack_blocks), 256, 0, stream>>>(
        batch_x, batch_a, keys, values, cnt, rowlist, qbuf, cellbuf,
        packed, B, prep_blocks);

    const int kps = (NKEYS + KSPLIT - 1) / KSPLIT;
    const dim3 grid(chunks, 3, KSPLIT);
    if (do_pack)
        main_kernel<1><<<grid, NTHR, 0, stream>>>(
            keys, values, packed, cnt, rowlist, qbuf, partial, B, kps);
    else
        main_kernel<0><<<grid, NTHR, 0, stream>>>(
            keys, values, packed, cnt, rowlist, qbuf, partial, B, kps);

    final_kernel<<<dim3(chunks), 256, 0, stream>>>(
        batch_x, partial, cellbuf, out_x, out_unc, out_done, B);
}

// Round 7
// 75.958 us; speedup vs baseline: 3.7960x; 1.0376x over previous
//
#include <hip/hip_runtime.h>
#include <math.h>

#define GRID_D 362
#define NKEYS  10000
#define EPSV   1e-8f
#define MROWS  8
#define NTHR   256
#define RPB    16    // rows per prep block
#define KSPLIT 4
#define LOG2E  1.4426950408889634f
#define LN2    0.6931471805599453f

__device__ __forceinline__ float rfl(float x) {
    return __int_as_float(__builtin_amdgcn_readfirstlane(__float_as_int(x)));
}

// ---------- prep (16 rows/block, LDS histogram -> 3 atomics/block) + pack ----------
__global__ __launch_bounds__(256) void prep_pack_kernel(
    const float* __restrict__ batch_x,
    const int*   __restrict__ batch_a,
    const float* __restrict__ keys,      // [3*10000, 6]
    const float* __restrict__ values,    // [3*10000, 7]
    int*   __restrict__ cnt,             // [4] zeroed
    int*   __restrict__ rowlist,         // [3*B]
    float* __restrict__ qout,            // [B*6]  (pre-scaled by LOG2E)
    int*   __restrict__ cellout,         // [B*6]
    float* __restrict__ packed,          // [3*10000, 16]
    int B, int prep_blocks)
{
    if ((int)blockIdx.x >= prep_blocks) {
        // ---- pack: one thread per key-row ----
        const int i = (blockIdx.x - prep_blocks) * 256 + threadIdx.x;
        if (i >= 3 * NKEYS) return;
        const float* k = keys   + (size_t)i * 6;
        const float* v = values + (size_t)i * 7;
        const float k0 = k[0], k1 = k[1], k2 = k[2], k3 = k[3], k4 = k[4], k5 = k[5];
        const float nn = k0*k0 + k1*k1 + k2*k2 + k3*k3 + k4*k4 + k5*k5;
        const float invn = 1.f / (sqrtf(nn) + EPSV);
        float4* p = (float4*)(packed + (size_t)i * 16);
        p[0] = make_float4(k0*invn, k1*invn, k2*invn, k3*invn);
        p[1] = make_float4(k4*invn, k5*invn, v[0], v[1]);
        p[2] = make_float4(v[2], v[3], v[4], v[5]);
        p[3] = make_float4(v[6], 0.f, 0.f, 0.f);
        return;
    }

    __shared__ int sh_a[RPB];
    __shared__ int sh_hist[3];
    __shared__ int sh_base[3];
    const int tid  = threadIdx.x;
    const int lane = tid & 63;
    const int w    = tid >> 6;
    if (tid < 3) sh_hist[tid] = 0;
    __syncthreads();

    const int b0 = blockIdx.x * RPB;
    for (int rr = 0; rr < RPB / 4; ++rr) {
        const int i = rr * 4 + w;
        const int b = b0 + i;
        if (b >= B) continue;                       // wave-uniform
        const float* x = batch_x + (size_t)b * GRID_D;
        float bestv = -INFINITY;
        int   besti = 1 << 30;
        for (int c = lane; c < GRID_D; c += 64) {
            const float vv = x[c];
            if (vv > bestv || (vv == bestv && c < besti)) { bestv = vv; besti = c; }
        }
#pragma unroll
        for (int off = 32; off > 0; off >>= 1) {
            const float ov = __shfl_down(bestv, off);
            const int   oi = __shfl_down(besti, off);
            if (ov > bestv || (ov == bestv && oi < besti)) { bestv = ov; besti = oi; }
        }
        if (lane == 0) {
            const int ptr = besti;
            int cells[6];
            cells[0] = 0;
            cells[1] = ptr;
            cells[2] = min(max(ptr - 19, 1), GRID_D - 1);
            cells[3] = min(max(ptr + 19, 1), GRID_D - 1);
            cells[4] = min(max(ptr - 1,  1), GRID_D - 1);
            cells[5] = min(max(ptr + 1,  1), GRID_D - 1);
            float att[6], ss = 0.f;
#pragma unroll
            for (int j = 0; j < 6; ++j) { att[j] = x[cells[j]]; ss += att[j] * att[j]; }
            const float inv = 1.f / (sqrtf(ss) + EPSV);
#pragma unroll
            for (int j = 0; j < 6; ++j) {
                qout[b * 6 + j]    = att[j] * inv * LOG2E;   // exp2-domain logits
                cellout[b * 6 + j] = cells[j];
            }
            const int a = batch_a[b];
            sh_a[i] = a;
            atomicAdd(&sh_hist[a], 1);              // LDS atomic
        }
    }
    __syncthreads();
    if (tid == 0) {
#pragma unroll
        for (int a = 0; a < 3; ++a) sh_base[a] = atomicAdd(&cnt[a], sh_hist[a]);
    }
    __syncthreads();
    if (tid < RPB && b0 + tid < B) {
        const int a = sh_a[tid];
        int pos = 0;
        for (int j = 0; j < tid; ++j) pos += (sh_a[j] == a) ? 1 : 0;
        rowlist[a * B + sh_base[a] + pos] = b0 + tid;
    }
}

// ---------- main: 8 rows/block, z = key-slice, write partials only ----------
// __launch_bounds__(256, 4): 4 waves/EU -> up to 128 VGPRs so the 64 f32
// accumulators live in arch VGPRs (VGPR=60 build used AGPR round-trips).
template <int PACKED>
__global__ __launch_bounds__(NTHR, 4) void main_kernel(
    const float* __restrict__ keys,
    const float* __restrict__ values,
    const float* __restrict__ packed,
    const int*   __restrict__ cnt,
    const int*   __restrict__ rowlist,
    const float* __restrict__ qin,
    float* __restrict__ partial,         // [KSPLIT][B][9]
    int B, int kps)
{
    const int a     = blockIdx.y;
    const int base  = blockIdx.x * MROWS;
    const int count = cnt[a];
    if (base >= count) return;
    const int tid  = threadIdx.x;
    const int lane = tid & 63;
    const int w    = tid >> 6;
    const int z    = blockIdx.z;

    __shared__ int   s_row[MROWS];
    __shared__ float s_q[MROWS][6];
    __shared__ float s_red[4][64];
    __shared__ float s_redm[4][MROWS];

    if (tid < MROWS)
        s_row[tid] = (base + tid < count) ? rowlist[a * B + base + tid] : -1;
    if (tid < MROWS * 6) {
        const int r = tid / 6, j = tid % 6;
        const int row = (base + r < count) ? rowlist[a * B + base + r] : -1;
        s_q[r][j] = (row >= 0) ? qin[row * 6 + j] : 0.f;
    }
    __syncthreads();

    // wave-uniform query coefficients (SGPRs), already scaled by LOG2E
    float qs[MROWS][6];
#pragma unroll
    for (int r = 0; r < MROWS; ++r)
#pragma unroll
        for (int j = 0; j < 6; ++j) qs[r][j] = rfl(s_q[r][j]);

    float acc[64];
    float m[MROWS];
#pragma unroll
    for (int i = 0; i < 64; ++i) acc[i] = 0.f;
#pragma unroll
    for (int r = 0; r < MROWS; ++r) m[r] = -INFINITY;

    const int n0 = z * kps;
    const int n1 = min(n0 + kps, NKEYS);

    if (PACKED) {
        const float4* __restrict__ pk = (const float4*)packed + (size_t)a * NKEYS * 4;
        for (int n = n0 + tid; n < n1; n += 2 * NTHR) {
            const int  n2 = n + NTHR;
            const bool h2 = (n2 < n1);
            const float4 A0 = pk[n * 4 + 0], A1 = pk[n * 4 + 1],
                         A2 = pk[n * 4 + 2], A3 = pk[n * 4 + 3];
            float4 B0, B1, B2, B3;
            if (h2) { B0 = pk[n2 * 4 + 0]; B1 = pk[n2 * 4 + 1];
                      B2 = pk[n2 * 4 + 2]; B3 = pk[n2 * 4 + 3]; }
            {
                const float v0 = A1.z, v1 = A1.w, v2 = A2.x, v3 = A2.y,
                            v4 = A2.z, v5 = A2.w, v6 = A3.x;
#pragma unroll
                for (int r = 0; r < MROWS; ++r) {
                    const float s = qs[r][0]*A0.x + qs[r][1]*A0.y + qs[r][2]*A0.z +
                                    qs[r][3]*A0.w + qs[r][4]*A1.x + qs[r][5]*A1.y;
                    m[r] = fmaxf(m[r], s);
                    const float e = __builtin_amdgcn_exp2f(s - LOG2E); // == exp(sim-1)
                    acc[r*8+0] += e;
                    acc[r*8+1] += e*v0; acc[r*8+2] += e*v1; acc[r*8+3] += e*v2;
                    acc[r*8+4] += e*v3; acc[r*8+5] += e*v4; acc[r*8+6] += e*v5;
                    acc[r*8+7] += e*v6;
                }
            }
            if (h2) {
                const float v0 = B1.z, v1 = B1.w, v2 = B2.x, v3 = B2.y,
                            v4 = B2.z, v5 = B2.w, v6 = B3.x;
#pragma unroll
                for (int r = 0; r < MROWS; ++r) {
                    const float s = qs[r][0]*B0.x + qs[r][1]*B0.y + qs[r][2]*B0.z +
                                    qs[r][3]*B0.w + qs[r][4]*B1.x + qs[r][5]*B1.y;
                    m[r] = fmaxf(m[r], s);
                    const float e = __builtin_amdgcn_exp2f(s - LOG2E);
                    acc[r*8+0] += e;
                    acc[r*8+1] += e*v0; acc[r*8+2] += e*v1; acc[r*8+3] += e*v2;
                    acc[r*8+4] += e*v3; acc[r*8+5] += e*v4; acc[r*8+6] += e*v5;
                    acc[r*8+7] += e*v6;
                }
            }
        }
    } else {
        const float* __restrict__ krow = keys   + (size_t)a * NKEYS * 6;
        const float* __restrict__ vrow = values + (size_t)a * NKEYS * 7;
        for (int n = n0 + tid; n < n1; n += NTHR) {
            const float* kp = krow + n * 6;
            const float2 k01 = *(const float2*)(kp);
            const float2 k23 = *(const float2*)(kp + 2);
            const float2 k45 = *(const float2*)(kp + 4);
            const float nn = k01.x*k01.x + k01.y*k01.y + k23.x*k23.x +
                             k23.y*k23.y + k45.x*k45.x + k45.y*k45.y;
            const float invn = 1.f / (sqrtf(nn) + EPSV);
            const float* vp = vrow + n * 7;
            const float v0 = vp[0], v1 = vp[1], v2 = vp[2], v3 = vp[3],
                        v4 = vp[4], v5 = vp[5], v6 = vp[6];
#pragma unroll
            for (int r = 0; r < MROWS; ++r) {
                const float dot = qs[r][0]*k01.x + qs[r][1]*k01.y + qs[r][2]*k23.x +
                                  qs[r][3]*k23.y + qs[r][4]*k45.x + qs[r][5]*k45.y;
                const float s = dot * invn;
                m[r] = fmaxf(m[r], s);
                const float e = __builtin_amdgcn_exp2f(s - LOG2E);
                acc[r*8+0] += e;
                acc[r*8+1] += e*v0; acc[r*8+2] += e*v1; acc[r*8+3] += e*v2;
                acc[r*8+4] += e*v3; acc[r*8+5] += e*v4; acc[r*8+6] += e*v5;
                acc[r*8+7] += e*v6;
            }
        }
    }

    // ---- in-wave log reduce-scatter: lane l ends owning flat value l ----
#pragma unroll
    for (int bit = 32; bit >= 1; bit >>= 1) {
        const bool up = (lane & bit) != 0;
#pragma unroll
        for (int i = 0; i < bit; ++i) {
            const float send = up ? acc[i] : acc[i + bit];
            const float recv = __shfl_xor(send, bit);
            acc[i] = (up ? acc[i + bit] : acc[i]) + recv;
        }
    }
#pragma unroll
    for (int bit = 32; bit >= 8; bit >>= 1) {
        const int  c  = bit >> 3;
        const bool up = (lane & bit) != 0;
#pragma unroll
        for (int i = 0; i < c; ++i) {
            const float send = up ? m[i] : m[i + c];
            const float recv = __shfl_xor(send, bit);
            m[i] = fmaxf(up ? m[i + c] : m[i], recv);
        }
    }
    float m0 = m[0];
#pragma unroll
    for (int bit = 4; bit >= 1; bit >>= 1) m0 = fmaxf(m0, __shfl_xor(m0, bit));

    s_red[w][lane] = acc[0];
    if ((lane & 7) == 0) s_redm[w][lane >> 3] = m0;
    __syncthreads();

    // ---- cross-wave combine, write partials (no fences: finalize is a new kernel) ----
    if (tid < 64) {
        const float t = s_red[0][tid] + s_red[1][tid] + s_red[2][tid] + s_red[3][tid];
        const int r = tid >> 3, row = s_row[r];
        if (row >= 0) partial[((size_t)z * B + row) * 9 + (tid & 7)] = t;
    } else if (tid < 64 + MROWS) {
        const int r = tid - 64;
        const float mm = fmaxf(fmaxf(s_redm[0][r], s_redm[1][r]),
                               fmaxf(s_redm[2][r], s_redm[3][r]));
        const int row = s_row[r];
        if (row >= 0) partial[((size_t)z * B + row) * 9 + 8] = mm * LN2; // unscale
    }
}

// ---------- finalize: combine splits per row, write outputs (8 rows/block) ----------
__global__ __launch_bounds__(256) void final_kernel(
    const float* __restrict__ batch_x,
    const float* __restrict__ partial,   // [KSPLIT][B][9]
    const int*   __restrict__ cellin,
    float* __restrict__ out_x,
    float* __restrict__ out_unc,
    float* __restrict__ out_done,
    int B)
{
    const int b0  = blockIdx.x * MROWS;
    const int tid = threadIdx.x;

    __shared__ float s_tot[MROWS][9];
    __shared__ float s_delta[MROWS][6];
    __shared__ int   s_cell[MROWS][6];

    if (tid < MROWS * 9) {
        const int r = tid / 9, p = tid % 9;
        const int row = b0 + r;
        if (row < B) {
            float v = partial[(size_t)row * 9 + p];
#pragma unroll
            for (int z = 1; z < KSPLIT; ++z) {
                const float u = partial[((size_t)z * B + row) * 9 + p];
                v = (p == 8) ? fmaxf(v, u) : (v + u);
            }
            s_tot[r][p] = v;
        }
    }
    if (tid >= 128 && tid < 128 + MROWS * 6) {
        const int t = tid - 128, r = t / 6, j = t % 6;
        if (b0 + r < B) s_cell[r][j] = cellin[(b0 + r) * 6 + j];
    }
    __syncthreads();
    if (tid < MROWS) {
        const int r = tid, row = b0 + r;
        if (row < B) {
            const float inv = 1.f / s_tot[r][0];
#pragma unroll
            for (int j = 0; j < 6; ++j) s_delta[r][j] = s_tot[r][1 + j] * inv;
            out_done[row] = s_tot[r][7] * inv;
            out_unc[row]  = -s_tot[r][8];
        }
    }
    __syncthreads();

    for (int f = tid; f < MROWS * GRID_D; f += 256) {
        const int r = f / GRID_D;
        const int c = f - r * GRID_D;
        const int row = b0 + r;
        if (row >= B) continue;
        float add = 0.f;
#pragma unroll
        for (int j = 0; j < 6; ++j)
            if (s_cell[r][j] == c) add = s_delta[r][j];   // ascending j: last wins
        out_x[(size_t)row * GRID_D + c] = batch_x[(size_t)row * GRID_D + c] + add;
    }
}

extern "C" void kernel_launch(void* const* d_in, const int* in_sizes, int n_in,
                              void* d_out, int out_size, void* d_ws, size_t ws_size,
                              hipStream_t stream) {
    const float* batch_x = (const float*)d_in[0];
    const int*   batch_a = (const int*)d_in[1];
    const float* keys    = (const float*)d_in[2];
    const float* values  = (const float*)d_in[3];
    const int B = in_sizes[1];                 // 4096

    float* out      = (float*)d_out;
    float* out_x    = out;
    float* out_unc  = out + (size_t)B * GRID_D;
    float* out_done = out_unc + B;

    const int chunks = (B + MROWS - 1) / MROWS;      // 512

    // workspace layout
    int*   cnt     = (int*)d_ws;                         // 4 ints (zeroed)
    int*   rowlist = cnt + 4;                            // 3*B ints
    float* qbuf    = (float*)(rowlist + 3 * B);          // B*6 floats
    int*   cellbuf = (int*)(qbuf + (size_t)B * 6);       // B*6 ints
    float* partial = (float*)(cellbuf + (size_t)B * 6);  // KSPLIT*B*9 floats
    float* packed  = (float*)(partial + (size_t)KSPLIT * B * 9);

    const size_t fixed_elems = (size_t)4 + 3 * B + 6 * B + 6 * B + (size_t)KSPLIT * B * 9;
    const size_t pack_elems  = (size_t)3 * NKEYS * 16;
    const int do_pack = (ws_size >= (fixed_elems + pack_elems) * 4) ? 1 : 0;

    hipMemsetAsync(cnt, 0, 4 * sizeof(int), stream);

    const int prep_blocks = (B + RPB - 1) / RPB;
    const int pack_blocks = do_pack ? (3 * NKEYS + 255) / 256 : 0;
    prep_pack_kernel<<<dim3(prep_blocks + pack_blocks), 256, 0, stream>>>(
        batch_x, batch_a, keys, values, cnt, rowlist, qbuf, cellbuf,
        packed, B, prep_blocks);

    const int kps = (NKEYS + KSPLIT - 1) / KSPLIT;
    const dim3 grid(chunks, 3, KSPLIT);
    if (do_pack)
        main_kernel<1><<<grid, NTHR, 0, stream>>>(
            keys, values, packed, cnt, rowlist, qbuf, partial, B, kps);
    else
        main_kernel<0><<<grid, NTHR, 0, stream>>>(
            keys, values, packed, cnt, rowlist, qbuf, partial, B, kps);

    final_kernel<<<dim3(chunks), 256, 0, stream>>>(
        batch_x, partial, cellbuf, out_x, out_unc, out_done, B);
}

// Round 8
// 63.278 us; speedup vs baseline: 4.5567x; 1.2004x over previous
//
#include <hip/hip_runtime.h>
#include <hip/hip_bf16.h>
#include <math.h>

#define GRID_D 362
#define NKEYS  10000
#define NKPAD  10240            // padded to KSPLIT*4waves*64
#define NT32   320              // NKPAD/32
#define EPSV   1e-8f
#define MROWS  8
#define NTHR   256
#define RPB    16
#define KSPLIT 4
#define KPS    2560             // NKPAD/KSPLIT
#define LOG2E  1.4426950408889634f
#define LN2    0.6931471805599453f

typedef unsigned short u16;
typedef unsigned int   u32;
typedef __attribute__((ext_vector_type(8))) short bf16x8;
typedef __attribute__((ext_vector_type(4))) float f32x4;

__device__ __forceinline__ float rfl(float x) {
    return __int_as_float(__builtin_amdgcn_readfirstlane(__float_as_int(x)));
}
__device__ __forceinline__ u16 f2bf(float x) {
    __hip_bfloat16 b = __float2bfloat16(x);
    return *reinterpret_cast<u16*>(&b);
}

// ---------- prep rows (histogram bucketing) + K-pack (f32x8) + V-frag pack (bf16 B-layout) ----------
__global__ __launch_bounds__(256) void prep_pack_kernel(
    const float* __restrict__ batch_x,
    const int*   __restrict__ batch_a,
    const float* __restrict__ keys,      // [3,10000,6]
    const float* __restrict__ values,    // [3,10000,7]
    int*   __restrict__ cnt,             // [4] zeroed
    int*   __restrict__ rowlist,         // [3*B]
    float* __restrict__ qout,            // [B*6] scaled by LOG2E
    int*   __restrict__ cellout,         // [B*6]
    float* __restrict__ kpack,           // [3*NKPAD*8] normalized keys
    uint4* __restrict__ vfrag,           // [3*NT32*64] B-fragments
    int B, int prep_blocks)
{
    const int bid = blockIdx.x;
    const int tid = threadIdx.x;

    if (bid >= prep_blocks + 120) {
        // ---- V-frag pack: thread <-> (a, t32, lane) ----
        const int i   = (bid - prep_blocks - 120) * 256 + tid;   // 0..61439
        const int a   = i / (NT32 * 64);
        const int rem = i - a * (NT32 * 64);
        const int t32 = rem >> 6;
        const int l   = rem & 63;
        const int col = l & 15;
        const int g   = l >> 4;
        u16 u[8];
#pragma unroll
        for (int j = 0; j < 8; ++j) {
            const int key = t32 * 32 + g * 8 + j;
            float v = 0.f;
            if (key < NKEYS) {
                if (col < 7)       v = values[((size_t)a * NKEYS + key) * 7 + col];
                else if (col == 7) v = 1.f;                      // sumexp column
            }
            u[j] = f2bf(v);
        }
        uint4 o;
        o.x = (u32)u[0] | ((u32)u[1] << 16);
        o.y = (u32)u[2] | ((u32)u[3] << 16);
        o.z = (u32)u[4] | ((u32)u[5] << 16);
        o.w = (u32)u[6] | ((u32)u[7] << 16);
        vfrag[i] = o;
        return;
    }
    if (bid >= prep_blocks) {
        // ---- K-pack: normalized key -> 32B row (zero pad keys) ----
        const int i   = (bid - prep_blocks) * 256 + tid;   // 0..30719
        const int a   = i / NKPAD;
        const int key = i - a * NKPAD;
        float4 o0 = make_float4(0.f, 0.f, 0.f, 0.f);
        float4 o1 = make_float4(0.f, 0.f, 0.f, 0.f);
        if (key < NKEYS) {
            const float* k = keys + ((size_t)a * NKEYS + key) * 6;
            const float k0=k[0],k1=k[1],k2=k[2],k3=k[3],k4=k[4],k5=k[5];
            const float nn = k0*k0+k1*k1+k2*k2+k3*k3+k4*k4+k5*k5;
            const float invn = 1.f/(sqrtf(nn)+EPSV);
            o0 = make_float4(k0*invn, k1*invn, k2*invn, k3*invn);
            o1 = make_float4(k4*invn, k5*invn, 0.f, 0.f);
        }
        float4* p = (float4*)(kpack + (size_t)i * 8);
        p[0] = o0; p[1] = o1;
        return;
    }

    // ---- prep rows: 16 rows/block, LDS histogram -> 3 global atomics ----
    __shared__ int sh_a[RPB];
    __shared__ int sh_hist[3];
    __shared__ int sh_base[3];
    const int lane = tid & 63;
    const int w    = tid >> 6;
    if (tid < 3) sh_hist[tid] = 0;
    __syncthreads();

    const int b0 = bid * RPB;
    for (int rr = 0; rr < RPB / 4; ++rr) {
        const int i = rr * 4 + w;
        const int b = b0 + i;
        if (b >= B) continue;
        const float* x = batch_x + (size_t)b * GRID_D;
        float bestv = -INFINITY;
        int   besti = 1 << 30;
        for (int c = lane; c < GRID_D; c += 64) {
            const float vv = x[c];
            if (vv > bestv || (vv == bestv && c < besti)) { bestv = vv; besti = c; }
        }
#pragma unroll
        for (int off = 32; off > 0; off >>= 1) {
            const float ov = __shfl_down(bestv, off);
            const int   oi = __shfl_down(besti, off);
            if (ov > bestv || (ov == bestv && oi < besti)) { bestv = ov; besti = oi; }
        }
        if (lane == 0) {
            const int ptr = besti;
            int cells[6];
            cells[0] = 0;
            cells[1] = ptr;
            cells[2] = min(max(ptr - 19, 1), GRID_D - 1);
            cells[3] = min(max(ptr + 19, 1), GRID_D - 1);
            cells[4] = min(max(ptr - 1,  1), GRID_D - 1);
            cells[5] = min(max(ptr + 1,  1), GRID_D - 1);
            float att[6], ss = 0.f;
#pragma unroll
            for (int j = 0; j < 6; ++j) { att[j] = x[cells[j]]; ss += att[j]*att[j]; }
            const float inv = 1.f / (sqrtf(ss) + EPSV);
#pragma unroll
            for (int j = 0; j < 6; ++j) {
                qout[b * 6 + j]    = att[j] * inv * LOG2E;
                cellout[b * 6 + j] = cells[j];
            }
            const int aa = batch_a[b];
            sh_a[i] = aa;
            atomicAdd(&sh_hist[aa], 1);
        }
    }
    __syncthreads();
    if (tid == 0) {
#pragma unroll
        for (int aa = 0; aa < 3; ++aa) sh_base[aa] = atomicAdd(&cnt[aa], sh_hist[aa]);
    }
    __syncthreads();
    if (tid < RPB && b0 + tid < B) {
        const int aa = sh_a[tid];
        int pos = 0;
        for (int j = 0; j < tid; ++j) pos += (sh_a[j] == aa) ? 1 : 0;
        rowlist[aa * B + sh_base[aa] + pos] = b0 + tid;
    }
}

// ---------- main: VALU sim/exp + MFMA PV, 8 rows/block, z = key slice ----------
__global__ __launch_bounds__(NTHR) void main_kernel(
    const float* __restrict__ kpack,
    const bf16x8* __restrict__ vfrag,
    const int*   __restrict__ cnt,
    const int*   __restrict__ rowlist,
    const float* __restrict__ qin,
    float* __restrict__ partial,         // [KSPLIT][B][9]
    int B)
{
    const int a     = blockIdx.y;
    const int base  = blockIdx.x * MROWS;
    const int count = cnt[a];
    if (base >= count) return;
    const int tid  = threadIdx.x;
    const int lane = tid & 63;
    const int w    = tid >> 6;
    const int z    = blockIdx.z;

    __shared__ int   s_row[MROWS];
    __shared__ float s_q[MROWS][6];
    __shared__ u16   s_e[4][1024];       // per-wave [16 rows][64 keys], XOR-swizzled
    __shared__ float s_cred[4][8][8];
    __shared__ float s_redm[4][MROWS];

    if (tid < MROWS)
        s_row[tid] = (base + tid < count) ? rowlist[a * B + base + tid] : -1;
    if (tid < MROWS * 6) {
        const int r = tid / 6, j = tid % 6;
        const int row = (base + r < count) ? rowlist[a * B + base + r] : -1;
        s_q[r][j] = (row >= 0) ? qin[row * 6 + j] : 0.f;
    }
    // zero e rows 8..15 once (A rows 8-15 unused but keep defined)
    {
        uint4 zz = make_uint4(0u, 0u, 0u, 0u);
        *(uint4*)&s_e[w][512 + lane * 8] = zz;
    }
    __syncthreads();

    float qs[MROWS][6];
#pragma unroll
    for (int r = 0; r < MROWS; ++r)
#pragma unroll
        for (int j = 0; j < 6; ++j) qs[r][j] = rfl(s_q[r][j]);

    // constant per-lane LDS element indices (swizzle: elem = r*64 + (key ^ (r<<3)))
    int widx[8];
#pragma unroll
    for (int r = 0; r < 8; ++r) widx[r] = r * 64 + (lane ^ (r << 3));
    const int rr    = lane & 15;
    const int rsw   = (rr & 7) << 3;
    const int g8    = (lane >> 4) * 8;
    const int ridx0 = rr * 64 + ((0  + g8) ^ rsw);
    const int ridx1 = rr * 64 + ((32 + g8) ^ rsw);

    f32x4 c = {0.f, 0.f, 0.f, 0.f};
    float m[MROWS];
#pragma unroll
    for (int r = 0; r < MROWS; ++r) m[r] = -INFINITY;

    int keyg = z * KPS + w * 64 + lane;
    const float4*  kp = (const float4*)kpack + ((size_t)a * NKPAD + keyg) * 2;
    const bf16x8*  vp = vfrag + (((size_t)a * NT32 + (size_t)(z * 80 + w * 2)) * 64 + lane);

    for (int it = 0; it < 10; ++it) {        // 10 tiles of 64 keys per wave
        const float4 ka = kp[0];
        const float4 kb = kp[1];
        const bf16x8 b0 = vp[0];
        const bf16x8 b1 = vp[64];
        const bool valid = (keyg < NKEYS);
        u32 eb[8];
#pragma unroll
        for (int r = 0; r < MROWS; ++r) {
            float s = qs[r][0] * ka.x;
            s = fmaf(qs[r][1], ka.y, s);
            s = fmaf(qs[r][2], ka.z, s);
            s = fmaf(qs[r][3], ka.w, s);
            s = fmaf(qs[r][4], kb.x, s);
            s = fmaf(qs[r][5], kb.y, s);
            const float sv = valid ? s : -INFINITY;
            m[r] = fmaxf(m[r], sv);
            const float e = __builtin_amdgcn_exp2f(s);   // pad keys: e=1, V=0 -> harmless
            eb[r] = __float_as_uint(e);
        }
#pragma unroll
        for (int r = 0; r < MROWS; ++r)
            s_e[w][widx[r]] = (u16)(eb[r] >> 16);        // bf16 truncation (bias cancels in softmax)
        const bf16x8 a0 = *(const bf16x8*)&s_e[w][ridx0];
        const bf16x8 a1 = *(const bf16x8*)&s_e[w][ridx1];
        c = __builtin_amdgcn_mfma_f32_16x16x32_bf16(a0, b0, c, 0, 0, 0);
        c = __builtin_amdgcn_mfma_f32_16x16x32_bf16(a1, b1, c, 0, 0, 0);
        kp   += 512;     // 4 tiles * 64 keys * 2 float4
        vp   += 512;     // 4 tiles * 2 frags * 64 lanes
        keyg += 256;
    }

    // ---- max reduce: flat-8 over 64 lanes ----
#pragma unroll
    for (int bit = 32; bit >= 8; bit >>= 1) {
        const int  cc = bit >> 3;
        const bool up = (lane & bit) != 0;
#pragma unroll
        for (int i = 0; i < cc; ++i) {
            const float send = up ? m[i] : m[i + cc];
            const float recv = __shfl_xor(send, bit);
            m[i] = fmaxf(up ? m[i + cc] : m[i], recv);
        }
    }
    float m0 = m[0];
#pragma unroll
    for (int bit = 4; bit >= 1; bit >>= 1) m0 = fmaxf(m0, __shfl_xor(m0, bit));
    if ((lane & 7) == 0) s_redm[w][lane >> 3] = m0;

    // ---- C tile -> LDS (rows 0..7, cols 0..7 live in lanes {0..7,16..23}) ----
    if (lane < 32 && (lane & 15) < 8) {
        const int colp  = lane & 15;
        const int rbase = (lane >> 4) * 4;
#pragma unroll
        for (int gg = 0; gg < 4; ++gg) s_cred[w][rbase + gg][colp] = c[gg];
    }
    __syncthreads();

    // ---- cross-wave combine, write partials ----
    if (tid < 64) {
        const int r = tid >> 3, ci = tid & 7;
        const int row = s_row[r];
        if (row >= 0) {
            const float t = s_cred[0][r][ci] + s_cred[1][r][ci] +
                            s_cred[2][r][ci] + s_cred[3][r][ci];
            const int p = (ci == 7) ? 0 : (ci + 1);   // col7=sumexp->p0, cols0..6->p1..7
            partial[((size_t)z * B + row) * 9 + p] = t;
        }
    } else if (tid < 64 + MROWS) {
        const int r = tid - 64;
        const int row = s_row[r];
        if (row >= 0) {
            const float mm = fmaxf(fmaxf(s_redm[0][r], s_redm[1][r]),
                                   fmaxf(s_redm[2][r], s_redm[3][r]));
            partial[((size_t)z * B + row) * 9 + 8] = mm * LN2;   // back to e-domain sim
        }
    }
}

// ---------- finalize: combine splits per row, write outputs (8 rows/block) ----------
__global__ __launch_bounds__(256) void final_kernel(
    const float* __restrict__ batch_x,
    const float* __restrict__ partial,   // [KSPLIT][B][9]
    const int*   __restrict__ cellin,
    float* __restrict__ out_x,
    float* __restrict__ out_unc,
    float* __restrict__ out_done,
    int B)
{
    const int b0  = blockIdx.x * MROWS;
    const int tid = threadIdx.x;

    __shared__ float s_tot[MROWS][9];
    __shared__ float s_delta[MROWS][6];
    __shared__ int   s_cell[MROWS][6];

    if (tid < MROWS * 9) {
        const int r = tid / 9, p = tid % 9;
        const int row = b0 + r;
        if (row < B) {
            float v = partial[(size_t)row * 9 + p];
#pragma unroll
            for (int z = 1; z < KSPLIT; ++z) {
                const float u = partial[((size_t)z * B + row) * 9 + p];
                v = (p == 8) ? fmaxf(v, u) : (v + u);
            }
            s_tot[r][p] = v;
        }
    }
    if (tid >= 128 && tid < 128 + MROWS * 6) {
        const int t = tid - 128, r = t / 6, j = t % 6;
        if (b0 + r < B) s_cell[r][j] = cellin[(b0 + r) * 6 + j];
    }
    __syncthreads();
    if (tid < MROWS) {
        const int r = tid, row = b0 + r;
        if (row < B) {
            const float inv = 1.f / s_tot[r][0];
#pragma unroll
            for (int j = 0; j < 6; ++j) s_delta[r][j] = s_tot[r][1 + j] * inv;
            out_done[row] = s_tot[r][7] * inv;
            out_unc[row]  = -s_tot[r][8];
        }
    }
    __syncthreads();

    for (int f = tid; f < MROWS * GRID_D; f += 256) {
        const int r = f / GRID_D;
        const int c = f - r * GRID_D;
        const int row = b0 + r;
        if (row >= B) continue;
        float add = 0.f;
#pragma unroll
        for (int j = 0; j < 6; ++j)
            if (s_cell[r][j] == c) add = s_delta[r][j];   // ascending j: last wins
        out_x[(size_t)row * GRID_D + c] = batch_x[(size_t)row * GRID_D + c] + add;
    }
}

extern "C" void kernel_launch(void* const* d_in, const int* in_sizes, int n_in,
                              void* d_out, int out_size, void* d_ws, size_t ws_size,
                              hipStream_t stream) {
    const float* batch_x = (const float*)d_in[0];
    const int*   batch_a = (const int*)d_in[1];
    const float* keys    = (const float*)d_in[2];
    const float* values  = (const float*)d_in[3];
    const int B = in_sizes[1];                 // 4096

    float* out      = (float*)d_out;
    float* out_x    = out;
    float* out_unc  = out + (size_t)B * GRID_D;
    float* out_done = out_unc + B;

    const int chunks = (B + MROWS - 1) / MROWS;          // 512

    // workspace layout
    int*   cnt     = (int*)d_ws;                         // 4 ints (zeroed)
    int*   rowlist = cnt + 4;                            // 3*B
    float* qbuf    = (float*)(rowlist + 3 * B);          // B*6
    int*   cellbuf = (int*)(qbuf + (size_t)B * 6);       // B*6
    float* partial = (float*)(cellbuf + (size_t)B * 6);  // KSPLIT*B*9
    float* kpack   = partial + (size_t)KSPLIT * B * 9;   // 3*NKPAD*8
    uint4* vfrag   = (uint4*)(kpack + (size_t)3 * NKPAD * 8); // 3*NT32*64 uint4

    hipMemsetAsync(cnt, 0, 4 * sizeof(int), stream);

    const int prep_blocks = (B + RPB - 1) / RPB;         // 256
    const int grid_prep   = prep_blocks + 120 + 240;     // + kpack + vfrag segments
    prep_pack_kernel<<<grid_prep, 256, 0, stream>>>(
        batch_x, batch_a, keys, values, cnt, rowlist, qbuf, cellbuf,
        kpack, vfrag, B, prep_blocks);

    main_kernel<<<dim3(chunks, 3, KSPLIT), NTHR, 0, stream>>>(
        kpack, (const bf16x8*)vfrag, cnt, rowlist, qbuf, partial, B);

    final_kernel<<<dim3(chunks), 256, 0, stream>>>(
        batch_x, partial, cellbuf, out_x, out_unc, out_done, B);
}

// Round 9
// 56.311 us; speedup vs baseline: 5.1205x; 1.1237x over previous
//
#include <hip/hip_runtime.h>
#include <hip/hip_bf16.h>
#include <math.h>

#define GRID_D 362
#define NKEYS  10000
#define NKPAD  10240            // KSPLIT * 4 waves * 64 * 10
#define NT16   640              // NKPAD/16
#define NT32   320              // NKPAD/32
#define EPSV   1e-8f
#define MROWS  16               // rows per main block (one 16x16 MFMA tile)
#define FROWS  8                // rows per final block
#define NTHR   256
#define RPB    16               // rows per prep block
#define KSPLIT 4
#define KPS    2560             // NKPAD/KSPLIT
#define LOG2E  1.4426950408889634f
#define LN2    0.6931471805599453f

typedef unsigned short u16;
typedef unsigned int   u32;
typedef __attribute__((ext_vector_type(8))) short bf16x8;
typedef __attribute__((ext_vector_type(4))) float f32x4;

__device__ __forceinline__ u16 f2bf(float x) {
    __hip_bfloat16 b = __float2bfloat16(x);
    return *reinterpret_cast<u16*>(&b);
}

// ---------------- prep: row-prep | bucket-scan | K-frag pack | V-frag pack ----------------
__global__ __launch_bounds__(256) void prep_pack_kernel(
    const float* __restrict__ batch_x,
    const int*   __restrict__ batch_a,
    const float* __restrict__ keys,      // [3,10000,6]
    const float* __restrict__ values,    // [3,10000,7]
    int*   __restrict__ cnt,             // [4] (written by bucket block)
    int*   __restrict__ rowlist,         // [3*B]
    float* __restrict__ qout,            // [B*6] scaled by LOG2E
    int*   __restrict__ cellout,         // [B*6]
    uint4* __restrict__ kfc,             // [3*NT16*16] compact K B-frags (lanes 0-15)
    uint4* __restrict__ vfrag,           // [3*NT32*64] V B-frags
    int B, int prep_blocks)
{
    const int bid  = blockIdx.x;
    const int tid  = threadIdx.x;
    const int lane = tid & 63;
    const int w    = tid >> 6;

    __shared__ int s_wsum[3][4];

    if (bid > prep_blocks + 120) {
        // ---- V-frag pack: B-layout of mfma_16x16x32: col=l&15, k=(l>>4)*8+j ----
        const int i   = (bid - prep_blocks - 121) * 256 + tid;   // 0..61439
        const int a   = i / (NT32 * 64);
        const int rem = i - a * (NT32 * 64);
        const int t32 = rem >> 6;
        const int l   = rem & 63;
        const int col = l & 15;
        const int g   = l >> 4;
        u16 u[8];
#pragma unroll
        for (int j = 0; j < 8; ++j) {
            const int key = t32 * 32 + g * 8 + j;
            float v = 0.f;
            if (key < NKEYS) {
                if (col < 7)       v = values[((size_t)a * NKEYS + key) * 7 + col];
                else if (col == 7) v = 1.f;                      // sumexp column
            }
            u[j] = f2bf(v);
        }
        uint4 o;
        o.x = (u32)u[0] | ((u32)u[1] << 16);
        o.y = (u32)u[2] | ((u32)u[3] << 16);
        o.z = (u32)u[4] | ((u32)u[5] << 16);
        o.w = (u32)u[6] | ((u32)u[7] << 16);
        vfrag[i] = o;
        return;
    }
    if (bid > prep_blocks) {
        // ---- K-frag pack (compact): entry (a,t16,l16) = dims 0..7 (6 real) of key t16*16+l16 ----
        const int i   = (bid - prep_blocks - 1) * 256 + tid;     // 0..30719
        const int a   = i / (NT16 * 16);
        const int rem = i - a * (NT16 * 16);
        const int t16 = rem >> 4;
        const int l16 = rem & 15;
        const int key = t16 * 16 + l16;
        uint4 o = make_uint4(0u, 0u, 0u, 0u);
        if (key < NKEYS) {
            const float* k = keys + ((size_t)a * NKEYS + key) * 6;
            const float k0=k[0],k1=k[1],k2=k[2],k3=k[3],k4=k[4],k5=k[5];
            const float nn = k0*k0+k1*k1+k2*k2+k3*k3+k4*k4+k5*k5;
            const float invn = 1.f/(sqrtf(nn)+EPSV);
            o.x = (u32)f2bf(k0*invn) | ((u32)f2bf(k1*invn) << 16);
            o.y = (u32)f2bf(k2*invn) | ((u32)f2bf(k3*invn) << 16);
            o.z = (u32)f2bf(k4*invn) | ((u32)f2bf(k5*invn) << 16);
            o.w = 0u;
        }
        kfc[i] = o;
        return;
    }
    if (bid == prep_blocks) {
        // ---- bucket-scan block: stable partition of rows by a, no atomics ----
        int as[16];
        int c0 = 0, c1 = 0, c2 = 0;
#pragma unroll
        for (int i = 0; i < 16; ++i) {
            const int b = tid * 16 + i;
            const int aa = (b < B) ? batch_a[b] : -1;
            as[i] = aa;
            c0 += (aa == 0); c1 += (aa == 1); c2 += (aa == 2);
        }
        int x0 = c0, x1 = c1, x2 = c2;
#pragma unroll
        for (int off = 1; off < 64; off <<= 1) {
            const int y0 = __shfl_up(x0, off);
            const int y1 = __shfl_up(x1, off);
            const int y2 = __shfl_up(x2, off);
            if (lane >= off) { x0 += y0; x1 += y1; x2 += y2; }
        }
        if (lane == 63) { s_wsum[0][w] = x0; s_wsum[1][w] = x1; s_wsum[2][w] = x2; }
        __syncthreads();
        int b0 = 0, b1 = 0, b2 = 0;
        for (int ww = 0; ww < w; ++ww) {
            b0 += s_wsum[0][ww]; b1 += s_wsum[1][ww]; b2 += s_wsum[2][ww];
        }
        int o0 = b0 + x0 - c0;
        int o1 = b1 + x1 - c1;
        int o2 = b2 + x2 - c2;
#pragma unroll
        for (int i = 0; i < 16; ++i) {
            const int b = tid * 16 + i;
            if (b >= B) break;
            const int aa = as[i];
            if      (aa == 0) rowlist[0 * B + (o0++)] = b;
            else if (aa == 1) rowlist[1 * B + (o1++)] = b;
            else if (aa == 2) rowlist[2 * B + (o2++)] = b;
        }
        if (tid == 0) {
#pragma unroll
            for (int aa = 0; aa < 3; ++aa)
                cnt[aa] = s_wsum[aa][0] + s_wsum[aa][1] + s_wsum[aa][2] + s_wsum[aa][3];
        }
        return;
    }

    // ---- row-prep: 16 rows/block (4 waves x 4 rows): argmax -> q (LOG2E-scaled), cells ----
    const int b0r = bid * RPB;
    for (int rr = 0; rr < RPB / 4; ++rr) {
        const int b = b0r + rr * 4 + w;
        if (b >= B) continue;
        const float* x = batch_x + (size_t)b * GRID_D;
        float bestv = -INFINITY;
        int   besti = 1 << 30;
        for (int c = lane; c < GRID_D; c += 64) {
            const float vv = x[c];
            if (vv > bestv || (vv == bestv && c < besti)) { bestv = vv; besti = c; }
        }
#pragma unroll
        for (int off = 32; off > 0; off >>= 1) {
            const float ov = __shfl_down(bestv, off);
            const int   oi = __shfl_down(besti, off);
            if (ov > bestv || (ov == bestv && oi < besti)) { bestv = ov; besti = oi; }
        }
        if (lane == 0) {
            const int ptr = besti;
            int cells[6];
            cells[0] = 0;
            cells[1] = ptr;
            cells[2] = min(max(ptr - 19, 1), GRID_D - 1);
            cells[3] = min(max(ptr + 19, 1), GRID_D - 1);
            cells[4] = min(max(ptr - 1,  1), GRID_D - 1);
            cells[5] = min(max(ptr + 1,  1), GRID_D - 1);
            float att[6], ss = 0.f;
#pragma unroll
            for (int j = 0; j < 6; ++j) { att[j] = x[cells[j]]; ss += att[j]*att[j]; }
            const float inv = 1.f / (sqrtf(ss) + EPSV);
#pragma unroll
            for (int j = 0; j < 6; ++j) {
                qout[b * 6 + j]    = att[j] * inv * LOG2E;
                cellout[b * 6 + j] = cells[j];
            }
        }
    }
}

// ---------------- main: MFMA QK^T + MFMA PV, 16 rows/block, z = key slice ----------------
__global__ __launch_bounds__(NTHR) void main_kernel(
    const uint4* __restrict__ kfc,
    const bf16x8* __restrict__ vfrag,
    const int*   __restrict__ cnt,
    const int*   __restrict__ rowlist,
    const float* __restrict__ qin,
    float* __restrict__ partial,         // [KSPLIT][B][9]
    int B)
{
    const int a     = blockIdx.y;
    const int base  = blockIdx.x * MROWS;
    const int count = cnt[a];
    if (base >= count) return;
    const int tid  = threadIdx.x;
    const int lane = tid & 63;
    const int w    = tid >> 6;
    const int z    = blockIdx.z;

    __shared__ int   s_row[MROWS];
    __shared__ float s_q[MROWS][6];
    __shared__ u16   s_e[4][1024];       // per-wave [16 rows][64 keys], XOR-swizzled
    __shared__ float s_cred[4][MROWS][8];
    __shared__ float s_redm[4][MROWS];

    if (tid < MROWS)
        s_row[tid] = (base + tid < count) ? rowlist[a * B + base + tid] : -1;
    if (tid < MROWS * 6) {
        const int r = tid / 6, j = tid % 6;
        const int row = (base + r < count) ? rowlist[a * B + base + r] : -1;
        s_q[r][j] = (row >= 0) ? qin[row * 6 + j] : 0.f;
    }
    __syncthreads();

    // Q A-fragment (16x16x32): row = lane&15, k = (lane>>4)*8+j ; dims 6..31 = 0
    bf16x8 aq = {0,0,0,0,0,0,0,0};
    if (lane < 16) {
#pragma unroll
        for (int j = 0; j < 6; ++j) aq[j] = (short)f2bf(s_q[lane][j]);
    }

    // loop-invariant swizzled LDS write addresses: elem = row*64 + (key ^ ((row&7)<<3))
    int waddr[4][4];
#pragma unroll
    for (int t = 0; t < 4; ++t)
#pragma unroll
        for (int g = 0; g < 4; ++g) {
            const int row = ((lane >> 4) << 2) + g;
            const int key = t * 16 + (lane & 15);
            waddr[t][g] = row * 64 + (key ^ ((row & 7) << 3));
        }
    // PV A-frag read offsets (b128, consecutive after swizzle)
    const int rr  = lane & 15;
    const int rsw = (rr & 7) << 3;
    const int g8  = (lane >> 4) * 8;
    const int ridx0 = rr * 64 + (g8 ^ rsw);
    const int ridx1 = rr * 64 + ((32 + g8) ^ rsw);

    f32x4 c = {0.f, 0.f, 0.f, 0.f};
    float m[4];
#pragma unroll
    for (int g = 0; g < 4; ++g) m[g] = -INFINITY;

    const int kb0 = z * KPS + w * 64;                 // wave's first key
    const uint4*  kfp = kfc   + ((size_t)a * NT16 + (kb0 >> 4)) * 16 + (lane & 15);
    const bf16x8* vfp = vfrag + ((size_t)a * NT32 + (kb0 >> 5)) * 64 + lane;

    for (int it = 0; it < 10; ++it) {
        bf16x8 kf[4];
#pragma unroll
        for (int t = 0; t < 4; ++t) {
            uint4 u = make_uint4(0u, 0u, 0u, 0u);
            if (lane < 16) u = kfp[t * 16];
            kf[t] = *reinterpret_cast<bf16x8*>(&u);
        }
        const bf16x8 b0 = vfp[0];
        const bf16x8 b1 = vfp[64];

        f32x4 cs[4];
        const f32x4 zc = {0.f, 0.f, 0.f, 0.f};
#pragma unroll
        for (int t = 0; t < 4; ++t)
            cs[t] = __builtin_amdgcn_mfma_f32_16x16x32_bf16(aq, kf[t], zc, 0, 0, 0);

        const int kbase = kb0 + it * 256;
#pragma unroll
        for (int t = 0; t < 4; ++t) {
            const bool kv = (kbase + t * 16) < NKEYS;    // wave-uniform (10000 % 16 == 0)
#pragma unroll
            for (int g = 0; g < 4; ++g) {
                const float s = cs[t][g];
                if (kv) m[g] = fmaxf(m[g], s);
                const u32 eb = __float_as_uint(__builtin_amdgcn_exp2f(s));
                s_e[w][waddr[t][g]] = (u16)(eb >> 16);   // bf16 trunc (bias cancels)
            }
        }

        const bf16x8 a0 = *(const bf16x8*)&s_e[w][ridx0];
        const bf16x8 a1 = *(const bf16x8*)&s_e[w][ridx1];
        c = __builtin_amdgcn_mfma_f32_16x16x32_bf16(a0, b0, c, 0, 0, 0);
        c = __builtin_amdgcn_mfma_f32_16x16x32_bf16(a1, b1, c, 0, 0, 0);

        kfp += 256;      // 16 tiles * 16
        vfp += 512;      // 8 t32 * 64
    }

    // ---- per-row max: reduce across the 16 lanes sharing lane>>4 ----
#pragma unroll
    for (int off = 1; off < 16; off <<= 1)
#pragma unroll
        for (int g = 0; g < 4; ++g)
            m[g] = fmaxf(m[g], __shfl_xor(m[g], off));
    if ((lane & 15) == 0) {
#pragma unroll
        for (int g = 0; g < 4; ++g)
            s_redm[w][((lane >> 4) << 2) + g] = m[g];
    }
    // ---- C tile (16 rows x 8 cols) -> LDS ----
    if ((lane & 15) < 8) {
        const int ci = lane & 15;
        const int rb = (lane >> 4) << 2;
#pragma unroll
        for (int g = 0; g < 4; ++g) s_cred[w][rb + g][ci] = c[g];
    }
    __syncthreads();

    // ---- cross-wave combine, write partials ----
    if (tid < 128) {
        const int r = tid >> 3, ci = tid & 7;
        const int row = s_row[r];
        if (row >= 0) {
            const float t = s_cred[0][r][ci] + s_cred[1][r][ci] +
                            s_cred[2][r][ci] + s_cred[3][r][ci];
            const int p = (ci == 7) ? 0 : (ci + 1);
            partial[((size_t)z * B + row) * 9 + p] = t;
        }
    } else if (tid < 128 + MROWS) {
        const int r = tid - 128;
        const int row = s_row[r];
        if (row >= 0) {
            const float mm = fmaxf(fmaxf(s_redm[0][r], s_redm[1][r]),
                                   fmaxf(s_redm[2][r], s_redm[3][r]));
            partial[((size_t)z * B + row) * 9 + 8] = mm * LN2;
        }
    }
}

// ---------------- finalize: combine splits per row, write outputs ----------------
__global__ __launch_bounds__(256) void final_kernel(
    const float* __restrict__ batch_x,
    const float* __restrict__ partial,   // [KSPLIT][B][9]
    const int*   __restrict__ cellin,
    float* __restrict__ out_x,
    float* __restrict__ out_unc,
    float* __restrict__ out_done,
    int B)
{
    const int b0  = blockIdx.x * FROWS;
    const int tid = threadIdx.x;

    __shared__ float s_tot[FROWS][9];
    __shared__ float s_delta[FROWS][6];
    __shared__ int   s_cell[FROWS][6];

    if (tid < FROWS * 9) {
        const int r = tid / 9, p = tid % 9;
        const int row = b0 + r;
        if (row < B) {
            float v = partial[(size_t)row * 9 + p];
#pragma unroll
            for (int z = 1; z < KSPLIT; ++z) {
                const float u = partial[((size_t)z * B + row) * 9 + p];
                v = (p == 8) ? fmaxf(v, u) : (v + u);
            }
            s_tot[r][p] = v;
        }
    }
    if (tid >= 128 && tid < 128 + FROWS * 6) {
        const int t = tid - 128, r = t / 6, j = t % 6;
        if (b0 + r < B) s_cell[r][j] = cellin[(b0 + r) * 6 + j];
    }
    __syncthreads();
    if (tid < FROWS) {
        const int r = tid, row = b0 + r;
        if (row < B) {
            const float inv = 1.f / s_tot[r][0];
#pragma unroll
            for (int j = 0; j < 6; ++j) s_delta[r][j] = s_tot[r][1 + j] * inv;
            out_done[row] = s_tot[r][7] * inv;
            out_unc[row]  = -s_tot[r][8];
        }
    }
    __syncthreads();

    for (int f = tid; f < FROWS * GRID_D; f += 256) {
        const int r = f / GRID_D;
        const int c = f - r * GRID_D;
        const int row = b0 + r;
        if (row >= B) continue;
        float add = 0.f;
#pragma unroll
        for (int j = 0; j < 6; ++j)
            if (s_cell[r][j] == c) add = s_delta[r][j];   // ascending j: last wins
        out_x[(size_t)row * GRID_D + c] = batch_x[(size_t)row * GRID_D + c] + add;
    }
}

extern "C" void kernel_launch(void* const* d_in, const int* in_sizes, int n_in,
                              void* d_out, int out_size, void* d_ws, size_t ws_size,
                              hipStream_t stream) {
    const float* batch_x = (const float*)d_in[0];
    const int*   batch_a = (const int*)d_in[1];
    const float* keys    = (const float*)d_in[2];
    const float* values  = (const float*)d_in[3];
    const int B = in_sizes[1];                 // 4096

    float* out      = (float*)d_out;
    float* out_x    = out;
    float* out_unc  = out + (size_t)B * GRID_D;
    float* out_done = out_unc + B;

    // workspace layout (no memset needed: cnt/rowlist fully written by bucket block)
    int*   cnt     = (int*)d_ws;                         // 4
    int*   rowlist = cnt + 4;                            // 3*B
    float* qbuf    = (float*)(rowlist + 3 * B);          // B*6
    int*   cellbuf = (int*)(qbuf + (size_t)B * 6);       // B*6
    float* partial = (float*)(cellbuf + (size_t)B * 6);  // KSPLIT*B*9
    uint4* kfc     = (uint4*)(partial + (size_t)KSPLIT * B * 9); // 3*NT16*16
    uint4* vfrag   = kfc + (size_t)3 * NT16 * 16;        // 3*NT32*64

    const int prep_blocks = (B + RPB - 1) / RPB;         // 256
    const int grid_prep   = prep_blocks + 1 + 120 + 240; // rows | bucket | kfc | vfrag
    prep_pack_kernel<<<grid_prep, 256, 0, stream>>>(
        batch_x, batch_a, keys, values, cnt, rowlist, qbuf, cellbuf,
        kfc, vfrag, B, prep_blocks);

    const int chunks_m = (B + MROWS - 1) / MROWS;        // 256
    main_kernel<<<dim3(chunks_m, 3, KSPLIT), NTHR, 0, stream>>>(
        kfc, (const bf16x8*)vfrag, cnt, rowlist, qbuf, partial, B);

    const int chunks_f = (B + FROWS - 1) / FROWS;        // 512
    final_kernel<<<dim3(chunks_f), 256, 0, stream>>>(
        batch_x, partial, cellbuf, out_x, out_unc, out_done, B);
}